// Round 1
// 355.363 us; speedup vs baseline: 1.0231x; 1.0231x over previous
//
#include <hip/hip_runtime.h>

#define B 64
#define T 4096
#define U 256
#define SB 32            // pass1 blocks per batch
#define WPB 4            // waves per block
#define WBATCH (SB*WPB)  // 128 waves per batch
#define P2B 4            // pass2 blocks per batch

// ---------------- kernel 0: state[b,u] = decoder_s[b,:] @ Wa_w[:,u] + b[u] ----
// 4 partial accumulators break the 256-deep dependent FMA chain (latency-bound
// kernel on only 64 CUs; ILP halves its critical path).
__global__ __launch_bounds__(256) void state_kernel(
    const float* __restrict__ ds, const float* __restrict__ W,
    const float* __restrict__ bias, float* __restrict__ state)
{
    const int b = blockIdx.x, u = threadIdx.x;
    __shared__ float ss[U];
    ss[u] = ds[b * U + u];
    __syncthreads();
    float a0 = bias[u], a1 = 0.f, a2 = 0.f, a3 = 0.f;
#pragma unroll 4
    for (int d = 0; d < U; d += 4) {
        a0 = fmaf(ss[d + 0], W[(d + 0) * U + u], a0);
        a1 = fmaf(ss[d + 1], W[(d + 1) * U + u], a1);
        a2 = fmaf(ss[d + 2], W[(d + 2) * U + u], a2);
        a3 = fmaf(ss[d + 3], W[(d + 3) * U + u], a3);
    }
    state[b * U + u] = (a0 + a1) + (a2 + a3);
}

__device__ __forceinline__ int packed_len(const int* __restrict__ mb, int lane) {
    // left-packed mask length via 2 ballots (len >= 1024 guaranteed: T/4 min)
    const int s1 = mb[lane << 6];                           // sample stride 64
    const int k1 = __popcll(__ballot(s1 != 0));
    const int base = (k1 - 1) << 6;
    const int s2 = mb[base + lane];
    return base + __popcll(__ballot(s2 != 0));
}

// ---------------- kernel 1: fused score + online softmax + context partials ---
// b = blockIdx % B so consecutive blocks (-> same CU/XCD) mix batch lengths:
// balances the tail when short batches retire early.
__global__ __launch_bounds__(256) void pass1(
    const float* __restrict__ h, const int* __restrict__ mask,
    const float* __restrict__ state, float* __restrict__ score,
    float* __restrict__ pm, float* __restrict__ pl, float* __restrict__ pacc)
{
    const int b    = blockIdx.x & (B - 1);
    const int sblk = blockIdx.x >> 6;
    const int tid  = threadIdx.x;
    const int wave = tid >> 6, lane = tid & 63;
    const int wi   = sblk * WPB + wave;          // wave index within batch, 0..127

    // issue state + first h row BEFORE the two dependent ballot rounds of
    // packed_len: row wi (<=127) is always < len (len >= 1024), so the first
    // prefetch needs no guard and the warm-up latency overlaps.
    const float4 st = *(const float4*)(state + b * U + (lane << 2));
    const float* hb = h + (size_t)b * T * U;
    int t = wi;
    float4 hv = *(const float4*)(hb + (size_t)t * U + (lane << 2));

    const int len = packed_len(mask + b * T, lane);
    float*   scb = score + (size_t)b * T;

    float  m = -INFINITY, l = 0.f;
    float4 acc = make_float4(0.f, 0.f, 0.f, 0.f);

    while (t < len) {
        const int tn = t + WBATCH;
        const int tc = (tn < len) ? tn : t;      // clamped prefetch address
        const float4 hn = *(const float4*)(hb + (size_t)tc * U + (lane << 2));

        float p = st.x * hv.x + st.y * hv.y + st.z * hv.z + st.w * hv.w;
#pragma unroll
        for (int off = 32; off; off >>= 1) p += __shfl_xor(p, off, 64);
        if (lane == 0) scb[t] = p;               // stash raw score for pass2

        if (p > m) {                             // wave-uniform branch
            const float s0 = __expf(m - p);      // exp(-inf)=0 on first iter
            l = fmaf(l, s0, 1.0f);
            acc.x = fmaf(acc.x, s0, hv.x);
            acc.y = fmaf(acc.y, s0, hv.y);
            acc.z = fmaf(acc.z, s0, hv.z);
            acc.w = fmaf(acc.w, s0, hv.w);
            m = p;
        } else {
            const float e = __expf(p - m);
            l += e;
            acc.x = fmaf(e, hv.x, acc.x);
            acc.y = fmaf(e, hv.y, acc.y);
            acc.z = fmaf(e, hv.z, acc.z);
            acc.w = fmaf(e, hv.w, acc.w);
        }
        hv = hn;
        t  = tn;
    }

    // block-level reduce of 4 waves' (m, l, acc) -> one partial per block
    __shared__ float sm[WPB], sl[WPB];
    __shared__ float sacc[WPB * U];
    *(float4*)&sacc[wave * U + (lane << 2)] = acc;
    if (lane == 0) { sm[wave] = m; sl[wave] = l; }
    __syncthreads();

    const float M = fmaxf(fmaxf(sm[0], sm[1]), fmaxf(sm[2], sm[3]));
    float Lb = 0.f, a = 0.f;
#pragma unroll
    for (int w = 0; w < WPB; ++w) {
        const float sc = __expf(sm[w] - M);
        Lb += sl[w] * sc;
        a  += sacc[w * U + tid] * sc;
    }
    const int pidx = b * SB + sblk;
    if (tid == 0) { pm[pidx] = M; pl[pidx] = Lb; }
    pacc[(size_t)pidx * U + tid] = a;
}

// ---------------- kernel 2: combine partials, finalize ct and alpha -----------
// P2B blocks per batch: the alpha sweep previously ran on only 64 CUs; now 256
// blocks cover it (one float4 chunk per thread). Block part==0 also emits ct.
__global__ __launch_bounds__(256) void pass2(
    const int* __restrict__ mask, const float* __restrict__ pm,
    const float* __restrict__ pl, const float* __restrict__ pacc,
    float* __restrict__ ct, float* __restrict__ alpha)
{
    const int b    = blockIdx.x >> 2;            // P2B = 4
    const int part = blockIdx.x & (P2B - 1);
    const int tid  = threadIdx.x;
    const int lane = tid & 63;

    // M/L combine is tiny (32 scalars) and independent of len; every block
    // recomputes it rather than round-tripping through global.
    float M = -INFINITY;
#pragma unroll
    for (int s = 0; s < SB; ++s) M = fmaxf(M, pm[b * SB + s]);
    float L = 0.f;
#pragma unroll
    for (int s = 0; s < SB; ++s) L += pl[b * SB + s] * __expf(pm[b * SB + s] - M);
    const float invL = 1.f / L;

    const int len = packed_len(mask + b * T, lane);  // same result in all waves

    if (part == 0) {
        float a = 0.f;
#pragma unroll
        for (int s = 0; s < SB; ++s)
            a += pacc[(size_t)(b * SB + s) * U + tid] * __expf(pm[b * SB + s] - M);
        ct[b * U + tid] = a * invL;
    }

    float*  ap  = alpha + (size_t)b * T;
    float4* ab4 = (float4*)ap;
    const int i0 = part * (T / 4 / P2B);         // 256 chunks per part
    for (int i = i0 + tid; i < i0 + T / 4 / P2B; i += 256) {
        const int t0 = i << 2;
        float4 av;
        if (t0 + 4 <= len) {                     // fully valid chunk
            av = ab4[i];
            av.x = __expf(av.x - M) * invL;
            av.y = __expf(av.y - M) * invL;
            av.z = __expf(av.z - M) * invL;
            av.w = __expf(av.w - M) * invL;
        } else if (t0 >= len) {                  // fully padded: write zeros
            av = make_float4(0.f, 0.f, 0.f, 0.f);
        } else {                                 // boundary chunk
            av.x = (t0 + 0 < len) ? __expf(ap[t0 + 0] - M) * invL : 0.f;
            av.y = (t0 + 1 < len) ? __expf(ap[t0 + 1] - M) * invL : 0.f;
            av.z = (t0 + 2 < len) ? __expf(ap[t0 + 2] - M) * invL : 0.f;
            av.w = (t0 + 3 < len) ? __expf(ap[t0 + 3] - M) * invL : 0.f;
        }
        ab4[i] = av;
    }
}

extern "C" void kernel_launch(void* const* d_in, const int* in_sizes, int n_in,
                              void* d_out, int out_size, void* d_ws, size_t ws_size,
                              hipStream_t stream) {
    const float* h    = (const float*)d_in[0];   // [B,T,U]
    const float* ds   = (const float*)d_in[1];   // [B,D_DEC]
    const int*   mask = (const int*)d_in[2];     // [B,T]
    const float* W    = (const float*)d_in[3];   // [D_DEC,U]
    const float* bias = (const float*)d_in[4];   // [U]

    float* out   = (float*)d_out;
    float* ct    = out;                          // [B,U]
    float* alpha = out + B * U;                  // [B,T] (also score scratch)

    float* ws    = (float*)d_ws;
    float* state = ws;                           // B*U
    float* pm    = state + B * U;                // B*SB
    float* pl    = pm + B * SB;                  // B*SB
    float* pacc  = pl + B * SB;                  // B*SB*U

    state_kernel<<<B, 256, 0, stream>>>(ds, W, bias, state);
    pass1<<<B * SB, 256, 0, stream>>>(h, mask, state, alpha, pm, pl, pacc);
    pass2<<<B * P2B, 256, 0, stream>>>(mask, pm, pl, pacc, ct, alpha);
}